// Round 4
// baseline (318.279 us; speedup 1.0000x reference)
//
#include <hip/hip_runtime.h>
#include <hip/hip_bf16.h>
#include <stdint.h>

#define B_ 4
#define T_ 8192
#define D_ 512
#define H_ 512
#define M_ (B_ * T_)          // 32768 rows
#define NF 1024               // fused N: [0,512)=kz (Wz), [512,1024)=hp (Wh)
#define CHUNK 64
#define NCHUNK (T_ / CHUNK)   // 128

typedef __attribute__((ext_vector_type(8))) short short8;
typedef __attribute__((ext_vector_type(4))) float floatx4;

__device__ __forceinline__ unsigned short f2bf(float f) {
    union { float f; unsigned int u; } v; v.f = f;
    unsigned int u = v.u;
    u += 0x7fffu + ((u >> 16) & 1u);   // RNE
    return (unsigned short)(u >> 16);
}
__device__ __forceinline__ float2 bf2x2(unsigned int u) {
    union { unsigned int i; float f; } a, b;
    a.i = u << 16;            // low ushort = elem 0
    b.i = u & 0xffff0000u;    // high ushort = elem 1
    return make_float2(a.f, b.f);
}

// ---------------------------------------------------------------------------
// fused f32 -> bf16 converter for x, Wz, Wh (one launch)
// ---------------------------------------------------------------------------
__global__ void conv_all(const float* __restrict__ x,
                         const float* __restrict__ Wz,
                         const float* __restrict__ Wh,
                         unsigned short* __restrict__ xbf,
                         unsigned short* __restrict__ Wf)
{
    const int X4 = M_ * D_ / 4;        // 4,194,304
    const int W4 = H_ * D_ / 4;        // 65,536
    int i = blockIdx.x * blockDim.x + threadIdx.x;
    const float* src; unsigned short* dst; int idx;
    if (i < X4)            { src = x;  dst = xbf;                      idx = i; }
    else if (i < X4 + W4)  { src = Wz; dst = Wf;                       idx = i - X4; }
    else if (i < X4 + 2*W4){ src = Wh; dst = Wf + (size_t)H_ * D_;     idx = i - X4 - W4; }
    else return;
    float4 v = ((const float4*)src)[idx];
    ushort4 w; w.x = f2bf(v.x); w.y = f2bf(v.y); w.z = f2bf(v.z); w.w = f2bf(v.w);
    ((ushort4*)dst)[idx] = w;
}

// ---------------------------------------------------------------------------
// GEMM: pre[M][1024] = x[M][512] · Wf[1024][512]^T + bias
// 128x128 tile, BK=32, 4 waves, global_load_lds width=16, XOR-swizzled LDS.
// Operand roles SWAPPED (A=W rows, B=x rows) so each thread's 4 acc regs are
// 4 consecutive n -> epilogue is 16 coalesced 8-B stores (512 B/instr).
// Block swizzle is XCD-aware: all 8 n-blocks of one m-block on one XCD L2.
// ---------------------------------------------------------------------------
__global__ __launch_bounds__(256)
void gemm_pre(const unsigned short* __restrict__ xbf,
              const unsigned short* __restrict__ Wf,
              const float* __restrict__ bz, const float* __restrict__ bh,
              unsigned short* __restrict__ pre)
{
    __shared__ unsigned short lA[128 * 32];   // x tile (m-rows)
    __shared__ unsigned short lB[128 * 32];   // W tile (n-rows)

    const int tid  = threadIdx.x;
    const int lane = tid & 63;
    const int wave = tid >> 6;
    // XCD-aware swizzle: xcd = blk&7 (round-robin), 8 nblks per mblk stay on it
    const int xcd  = blockIdx.x & 7;
    const int nblk = (blockIdx.x >> 3) & 7;
    const int mblk = xcd * 32 + (blockIdx.x >> 6);
    const int m0 = mblk * 128;
    const int n0 = nblk * 128;
    const int wm = (wave >> 1) * 64;
    const int wn = (wave & 1) * 64;
    const int l15  = lane & 15;
    const int quad = lane >> 4;

    const int srow = lane >> 2;
    const int sp   = lane & 3;

    floatx4 acc[4][4];   // acc[i=m-frag][j=n-group]; regs r = consecutive n
    #pragma unroll
    for (int i = 0; i < 4; ++i)
        #pragma unroll
        for (int j = 0; j < 4; ++j) acc[i][j] = (floatx4)0.0f;

    for (int kt = 0; kt < D_ / 32; ++kt) {
        const int kb = kt * 32;
        __syncthreads();
        #pragma unroll
        for (int r = 0; r < 2; ++r) {
            const int chunk = r * 4 + wave;          // 0..7
            const int row   = chunk * 16 + srow;     // 0..127
            const int kp    = sp ^ (row & 3);        // swizzled source k-part
            __builtin_amdgcn_global_load_lds(
                (const __attribute__((address_space(1))) unsigned int*)
                    (xbf + (size_t)(m0 + row) * D_ + kb + kp * 8),
                (__attribute__((address_space(3))) unsigned int*)(lA + chunk * 512),
                16, 0, 0);
            __builtin_amdgcn_global_load_lds(
                (const __attribute__((address_space(1))) unsigned int*)
                    (Wf + (size_t)(n0 + row) * D_ + kb + kp * 8),
                (__attribute__((address_space(3))) unsigned int*)(lB + chunk * 512),
                16, 0, 0);
        }
        __syncthreads();

        short8 af[4], bf[4];
        #pragma unroll
        for (int i = 0; i < 4; ++i) {
            const int ra = wm + i * 16 + l15;
            af[i] = *(const short8*)&lA[ra * 32 + ((quad ^ (ra & 3)) * 8)];
            const int rb = wn + i * 16 + l15;
            bf[i] = *(const short8*)&lB[rb * 32 + ((quad ^ (rb & 3)) * 8)];
        }
        #pragma unroll
        for (int i = 0; i < 4; ++i)
            #pragma unroll
            for (int j = 0; j < 4; ++j)
                // A operand = W fragment (n side), B operand = x fragment (m side)
                // -> D row (quad*4+reg) = n, D col (lane&15) = m
                acc[i][j] = __builtin_amdgcn_mfma_f32_16x16x32_bf16(bf[j], af[i], acc[i][j], 0, 0, 0);
    }

    // epilogue: m = m0+wm+i*16+l15 ; n = n0+wn+j*16+quad*4+r  (r consecutive)
    const float* bias = (n0 < 512) ? (bz + n0) : (bh + (n0 - 512));
    #pragma unroll
    for (int i = 0; i < 4; ++i) {
        const int gm = m0 + wm + i * 16 + l15;
        #pragma unroll
        for (int j = 0; j < 4; ++j) {
            const int nl = wn + j * 16 + quad * 4;
            float4 bv = *(const float4*)&bias[nl];
            ushort4 w;
            w.x = f2bf(acc[i][j][0] + bv.x);
            w.y = f2bf(acc[i][j][1] + bv.y);
            w.z = f2bf(acc[i][j][2] + bv.z);
            w.w = f2bf(acc[i][j][3] + bv.w);
            *(ushort4*)&pre[(size_t)gm * NF + n0 + nl] = w;
        }
    }
}

// ---------------------------------------------------------------------------
// activation: c = sigmoid(-kz), d = (1-c) * g(hp)
// ---------------------------------------------------------------------------
__device__ __forceinline__ void act_cd(float kz, float hp, float& c, float& d) {
    c = 1.0f / (1.0f + __expf(kz));
    float z = 1.0f - c;
    float g = (hp >= 0.0f) ? (hp + 0.5f) : (1.0f / (1.0f + __expf(-hp)));
    d = z * g;
}

// ---------------------------------------------------------------------------
// chunk aggregates: 128 thr x 4 h each, uint2 loads, unroll 8
// ---------------------------------------------------------------------------
__global__ __launch_bounds__(128)
void chunk_scan(const unsigned short* __restrict__ pre,
                float* __restrict__ Cagg, float* __restrict__ Dagg)
{
    const int tid = threadIdx.x;                 // h = 4*tid
    const int j = blockIdx.x & (NCHUNK - 1);
    const int b = blockIdx.x >> 7;
    const unsigned short* base = pre + ((size_t)(b * T_ + j * CHUNK)) * NF + 4 * tid;
    float C[4] = {1.f, 1.f, 1.f, 1.f}, Dv[4] = {0.f, 0.f, 0.f, 0.f};
    #pragma unroll 8
    for (int t = 0; t < CHUNK; ++t) {
        uint2 kzu = *(const uint2*)(base + (size_t)t * NF);
        uint2 hpu = *(const uint2*)(base + (size_t)t * NF + 512);
        float2 kza = bf2x2(kzu.x), kzb = bf2x2(kzu.y);
        float2 hpa = bf2x2(hpu.x), hpb = bf2x2(hpu.y);
        float c, d;
        act_cd(kza.x, hpa.x, c, d); Dv[0] = fmaf(c, Dv[0], d); C[0] *= c;
        act_cd(kza.y, hpa.y, c, d); Dv[1] = fmaf(c, Dv[1], d); C[1] *= c;
        act_cd(kzb.x, hpb.x, c, d); Dv[2] = fmaf(c, Dv[2], d); C[2] *= c;
        act_cd(kzb.y, hpb.y, c, d); Dv[3] = fmaf(c, Dv[3], d); C[3] *= c;
    }
    size_t o = ((size_t)(b * NCHUNK + j)) * H_ + 4 * tid;
    *(float4*)&Cagg[o] = make_float4(C[0], C[1], C[2], C[3]);
    *(float4*)&Dagg[o] = make_float4(Dv[0], Dv[1], Dv[2], Dv[3]);
}

// ---------------------------------------------------------------------------
// inter-chunk sequential scan: 2048 chains spread over 32 blocks x 64 thr
// ---------------------------------------------------------------------------
__global__ __launch_bounds__(64)
void interchunk(const float* __restrict__ h_prev,
                const float* __restrict__ Cagg,
                const float* __restrict__ Dagg,
                float* __restrict__ Hstart)
{
    const int flat = blockIdx.x * 64 + threadIdx.x;
    const int b = flat >> 9;
    const int h = flat & 511;
    float hs = h_prev[(size_t)b * H_ + h];
    #pragma unroll 32
    for (int j = 0; j < NCHUNK; ++j) {
        size_t o = ((size_t)(b * NCHUNK + j)) * H_ + h;
        Hstart[o] = hs;
        hs = fmaf(Cagg[o], hs, Dagg[o]);
    }
}

// ---------------------------------------------------------------------------
// final apply: recompute c,d, scan within chunk, float4 stores to out
// ---------------------------------------------------------------------------
__global__ __launch_bounds__(128)
void apply_scan(const unsigned short* __restrict__ pre,
                const float* __restrict__ Hstart,
                float* __restrict__ out)
{
    const int tid = threadIdx.x;                 // h = 4*tid
    const int j = blockIdx.x & (NCHUNK - 1);
    const int b = blockIdx.x >> 7;
    float4 hs = *(const float4*)&Hstart[((size_t)(b * NCHUNK + j)) * H_ + 4 * tid];
    float h0 = hs.x, h1 = hs.y, h2 = hs.z, h3 = hs.w;
    const unsigned short* base = pre + ((size_t)(b * T_ + j * CHUNK)) * NF + 4 * tid;
    float* ob = out + ((size_t)(b * T_ + j * CHUNK)) * H_ + 4 * tid;
    #pragma unroll 8
    for (int t = 0; t < CHUNK; ++t) {
        uint2 kzu = *(const uint2*)(base + (size_t)t * NF);
        uint2 hpu = *(const uint2*)(base + (size_t)t * NF + 512);
        float2 kza = bf2x2(kzu.x), kzb = bf2x2(kzu.y);
        float2 hpa = bf2x2(hpu.x), hpb = bf2x2(hpu.y);
        float c, d;
        act_cd(kza.x, hpa.x, c, d); h0 = fmaf(c, h0, d);
        act_cd(kza.y, hpa.y, c, d); h1 = fmaf(c, h1, d);
        act_cd(kzb.x, hpb.x, c, d); h2 = fmaf(c, h2, d);
        act_cd(kzb.y, hpb.y, c, d); h3 = fmaf(c, h3, d);
        *(float4*)(ob + (size_t)t * H_) = make_float4(h0, h1, h2, h3);
    }
}

// ---------------------------------------------------------------------------
extern "C" void kernel_launch(void* const* d_in, const int* in_sizes, int n_in,
                              void* d_out, int out_size, void* d_ws, size_t ws_size,
                              hipStream_t stream)
{
    const float* x      = (const float*)d_in[0];
    const float* h_prev = (const float*)d_in[1];
    const float* W_h    = (const float*)d_in[2];
    const float* b_h    = (const float*)d_in[3];
    const float* W_z    = (const float*)d_in[4];
    const float* b_z    = (const float*)d_in[5];
    float* out = (float*)d_out;

    // xbf lives in d_out (dead until apply_scan overwrites all of it)
    unsigned short* xbf = (unsigned short*)d_out;               // 33.5 MB < 67 MB out

    char* ws = (char*)d_ws;
    unsigned short* pre = (unsigned short*)ws;                  // M*1024 bf16 = 67.1 MB
    size_t pre_bytes = (size_t)M_ * NF * sizeof(unsigned short);
    unsigned short* Wf = (unsigned short*)(ws + pre_bytes);     // 1 MB
    size_t wf_bytes = (size_t)NF * D_ * sizeof(unsigned short);
    float* Cagg   = (float*)(ws + pre_bytes + wf_bytes);        // 1 MB each
    float* Dagg   = Cagg + (size_t)B_ * NCHUNK * H_;
    float* Hstart = Dagg + (size_t)B_ * NCHUNK * H_;

    // 0) convert inputs to bf16 (single launch)
    {
        int total = M_ * D_ / 4 + 2 * (H_ * D_ / 4);
        conv_all<<<dim3((total + 255) / 256), dim3(256), 0, stream>>>(x, W_z, W_h, xbf, Wf);
    }
    // 1) fused GEMM -> raw preactivations (bf16)
    gemm_pre<<<dim3((M_ / 128) * (NF / 128)), dim3(256), 0, stream>>>(
        xbf, Wf, b_z, b_h, pre);
    // 2) chunk-local aggregates
    chunk_scan<<<dim3(B_ * NCHUNK), dim3(128), 0, stream>>>(pre, Cagg, Dagg);
    // 3) inter-chunk sequential scan
    interchunk<<<dim3(32), dim3(64), 0, stream>>>(h_prev, Cagg, Dagg, Hstart);
    // 4) final apply -> d_out (overwrites xbf scratch)
    apply_scan<<<dim3(B_ * NCHUNK), dim3(128), 0, stream>>>(pre, Hstart, out);
}

// Round 5
// 210.187 us; speedup vs baseline: 1.5143x; 1.5143x over previous
//
#include <hip/hip_runtime.h>
#include <hip/hip_bf16.h>
#include <stdint.h>

#define B_ 4
#define T_ 8192
#define D_ 512
#define H_ 512
#define M_ (B_ * T_)          // 32768 rows
#define CHUNK 64
#define NCHUNK (T_ / CHUNK)   // 128

typedef __attribute__((ext_vector_type(8))) short short8;
typedef __attribute__((ext_vector_type(4))) float floatx4;

__device__ __forceinline__ unsigned short f2bf(float f) {
    union { float f; unsigned int u; } v; v.f = f;
    unsigned int u = v.u;
    u += 0x7fffu + ((u >> 16) & 1u);   // RNE
    return (unsigned short)(u >> 16);
}
__device__ __forceinline__ float bf_lo(unsigned int u) {
    union { unsigned int i; float f; } a; a.i = u << 16; return a.f;
}
__device__ __forceinline__ float bf_hi(unsigned int u) {
    union { unsigned int i; float f; } a; a.i = u & 0xffff0000u; return a.f;
}
// pack (c,d) as bf16 pair into one dword: lo=c, hi=d
__device__ __forceinline__ unsigned int pk_cd(float c, float d) {
    return (unsigned int)f2bf(c) | ((unsigned int)f2bf(d) << 16);
}

// ---------------------------------------------------------------------------
// fused f32 -> bf16 converter for x, Wz, Wh (one launch)
// ---------------------------------------------------------------------------
__global__ void conv_all(const float* __restrict__ x,
                         const float* __restrict__ Wz,
                         const float* __restrict__ Wh,
                         unsigned short* __restrict__ xbf,
                         unsigned short* __restrict__ Wf)
{
    const int X4 = M_ * D_ / 4;
    const int W4 = H_ * D_ / 4;
    int i = blockIdx.x * blockDim.x + threadIdx.x;
    const float* src; unsigned short* dst; int idx;
    if (i < X4)             { src = x;  dst = xbf;                  idx = i; }
    else if (i < X4 + W4)   { src = Wz; dst = Wf;                   idx = i - X4; }
    else if (i < X4 + 2*W4) { src = Wh; dst = Wf + (size_t)H_ * D_; idx = i - X4 - W4; }
    else return;
    float4 v = ((const float4*)src)[idx];
    ushort4 w; w.x = f2bf(v.x); w.y = f2bf(v.y); w.z = f2bf(v.z); w.w = f2bf(v.w);
    ((ushort4*)dst)[idx] = w;
}

// ---------------------------------------------------------------------------
// Dual GEMM + fused activation epilogue.
//   kz = x·Wz^T + bz ; hp = x·Wh^T + bh  (both for the SAME (m, h) tile)
//   c = sigmoid(-kz); d = sigmoid(kz)*g(hp)   -> cd[m][h] = (c,d) bf16 pair
// 128x128 tile (m x h), BK=32, 4 waves, global_load_lds w=16, XOR swizzle.
// Operands swapped (A=W, B=x) -> thread holds 4 consecutive h per acc reg
// -> epilogue writes 16-B contiguous (c,d) pairs (dwordx4 stores).
// XCD-aware swizzle: all 4 h-blocks + 32-mblk band stay on one XCD L2.
// ---------------------------------------------------------------------------
__global__ __launch_bounds__(256, 2)
void gemm_cd(const unsigned short* __restrict__ xbf,
             const unsigned short* __restrict__ Wf,   // [0:512)=Wz rows, [512:1024)=Wh rows
             const float* __restrict__ bz, const float* __restrict__ bh,
             unsigned short* __restrict__ cd)
{
    __shared__ unsigned short lA[128 * 32];   // x tile
    __shared__ unsigned short lZ[128 * 32];   // Wz tile
    __shared__ unsigned short lH[128 * 32];   // Wh tile

    const int tid  = threadIdx.x;
    const int lane = tid & 63;
    const int wave = tid >> 6;
    // grid = 1024: bits [2:0]=xcd, [4:3]=hblk, [9:5]=m-band row
    const int xcd  = blockIdx.x & 7;
    const int nblk = (blockIdx.x >> 3) & 3;
    const int mblk = xcd * 32 + (blockIdx.x >> 5);
    const int m0 = mblk * 128;
    const int n0 = nblk * 128;                 // h offset
    const int wm = (wave >> 1) * 64;
    const int wn = (wave & 1) * 64;
    const int l15  = lane & 15;
    const int quad = lane >> 4;

    const int srow = lane >> 2;
    const int sp   = lane & 3;

    floatx4 acc_z[4][4], acc_h[4][4];
    #pragma unroll
    for (int i = 0; i < 4; ++i)
        #pragma unroll
        for (int j = 0; j < 4; ++j) { acc_z[i][j] = (floatx4)0.0f; acc_h[i][j] = (floatx4)0.0f; }

    for (int kt = 0; kt < D_ / 32; ++kt) {
        const int kb = kt * 32;
        __syncthreads();
        #pragma unroll
        for (int r = 0; r < 2; ++r) {
            const int chunk = r * 4 + wave;          // 0..7
            const int row   = chunk * 16 + srow;     // 0..127
            const int kp    = sp ^ (row & 3);        // swizzled source k-part
            __builtin_amdgcn_global_load_lds(
                (const __attribute__((address_space(1))) unsigned int*)
                    (xbf + (size_t)(m0 + row) * D_ + kb + kp * 8),
                (__attribute__((address_space(3))) unsigned int*)(lA + chunk * 512),
                16, 0, 0);
            __builtin_amdgcn_global_load_lds(
                (const __attribute__((address_space(1))) unsigned int*)
                    (Wf + (size_t)(n0 + row) * D_ + kb + kp * 8),
                (__attribute__((address_space(3))) unsigned int*)(lZ + chunk * 512),
                16, 0, 0);
            __builtin_amdgcn_global_load_lds(
                (const __attribute__((address_space(1))) unsigned int*)
                    (Wf + (size_t)(512 + n0 + row) * D_ + kb + kp * 8),
                (__attribute__((address_space(3))) unsigned int*)(lH + chunk * 512),
                16, 0, 0);
        }
        __syncthreads();

        short8 af[4], zf[4], hf[4];
        #pragma unroll
        for (int i = 0; i < 4; ++i) {
            const int ra = wm + i * 16 + l15;
            af[i] = *(const short8*)&lA[ra * 32 + ((quad ^ (ra & 3)) * 8)];
            const int rb = wn + i * 16 + l15;
            zf[i] = *(const short8*)&lZ[rb * 32 + ((quad ^ (rb & 3)) * 8)];
            hf[i] = *(const short8*)&lH[rb * 32 + ((quad ^ (rb & 3)) * 8)];
        }
        #pragma unroll
        for (int i = 0; i < 4; ++i)
            #pragma unroll
            for (int j = 0; j < 4; ++j) {
                // A=W frag (h side), B=x frag (m side): D row=h, D col=m
                acc_z[i][j] = __builtin_amdgcn_mfma_f32_16x16x32_bf16(zf[j], af[i], acc_z[i][j], 0, 0, 0);
                acc_h[i][j] = __builtin_amdgcn_mfma_f32_16x16x32_bf16(hf[j], af[i], acc_h[i][j], 0, 0, 0);
            }
    }

    // epilogue: m = m0+wm+i*16+l15 ; h = n0+wn+j*16+quad*4+r (r consecutive)
    #pragma unroll
    for (int j = 0; j < 4; ++j) {
        const int hl = n0 + wn + j * 16 + quad * 4;
        const float4 bzv = *(const float4*)&bz[hl];
        const float4 bhv = *(const float4*)&bh[hl];
        #pragma unroll
        for (int i = 0; i < 4; ++i) {
            const int gm = m0 + wm + i * 16 + l15;
            uint4 w;
            #pragma unroll
            for (int r = 0; r < 4; ++r) {
                float kz = acc_z[i][j][r] + ((const float*)&bzv)[r];
                float hp = acc_h[i][j][r] + ((const float*)&bhv)[r];
                float c  = 1.0f / (1.0f + __expf(kz));   // sigmoid(-kz)
                float g  = (hp >= 0.0f) ? (hp + 0.5f) : (1.0f / (1.0f + __expf(-hp)));
                float d  = (1.0f - c) * g;
                ((unsigned int*)&w)[r] = pk_cd(c, d);
            }
            // byte offset = 4*(gm*512 + hl); hl % 4 == 0 -> 16-B aligned
            *(uint4*)&cd[((size_t)gm * H_ + hl) * 2] = w;
        }
    }
}

// ---------------------------------------------------------------------------
// chunk aggregates: pure-fma stream over (c,d) pairs. 256 thr x 2 h.
// grid = B*NCHUNK = 512 blocks -> 8 waves/CU.
// ---------------------------------------------------------------------------
__global__ __launch_bounds__(256)
void chunk_scan(const unsigned short* __restrict__ cd,
                float* __restrict__ Cagg, float* __restrict__ Dagg)
{
    const int tid = threadIdx.x;                 // h = 2*tid
    const int j = blockIdx.x & (NCHUNK - 1);
    const int b = blockIdx.x >> 7;
    const unsigned short* base = cd + (size_t)(b * T_ + j * CHUNK) * (H_ * 2) + 4 * tid;
    float C0 = 1.f, C1 = 1.f, D0 = 0.f, D1 = 0.f;
    #pragma unroll 16
    for (int t = 0; t < CHUNK; ++t) {
        uint2 v = *(const uint2*)(base + (size_t)t * (H_ * 2));
        float c0 = bf_lo(v.x), d0 = bf_hi(v.x);
        float c1 = bf_lo(v.y), d1 = bf_hi(v.y);
        D0 = fmaf(c0, D0, d0);  C0 *= c0;
        D1 = fmaf(c1, D1, d1);  C1 *= c1;
    }
    size_t o = ((size_t)(b * NCHUNK + j)) * H_ + 2 * tid;
    *(float2*)&Cagg[o] = make_float2(C0, C1);
    *(float2*)&Dagg[o] = make_float2(D0, D1);
}

// ---------------------------------------------------------------------------
// inter-chunk sequential scan: 2048 chains over 32 blocks x 64 thr
// ---------------------------------------------------------------------------
__global__ __launch_bounds__(64)
void interchunk(const float* __restrict__ h_prev,
                const float* __restrict__ Cagg,
                const float* __restrict__ Dagg,
                float* __restrict__ Hstart)
{
    const int flat = blockIdx.x * 64 + threadIdx.x;
    const int b = flat >> 9;
    const int h = flat & 511;
    float hs = h_prev[(size_t)b * H_ + h];
    #pragma unroll 16
    for (int j = 0; j < NCHUNK; ++j) {
        size_t o = ((size_t)(b * NCHUNK + j)) * H_ + h;
        Hstart[o] = hs;
        hs = fmaf(Cagg[o], hs, Dagg[o]);
    }
}

// ---------------------------------------------------------------------------
// final apply: pure-fma stream, float2 stores. 256 thr x 2 h.
// ---------------------------------------------------------------------------
__global__ __launch_bounds__(256)
void apply_scan(const unsigned short* __restrict__ cd,
                const float* __restrict__ Hstart,
                float* __restrict__ out)
{
    const int tid = threadIdx.x;                 // h = 2*tid
    const int j = blockIdx.x & (NCHUNK - 1);
    const int b = blockIdx.x >> 7;
    float2 hs = *(const float2*)&Hstart[((size_t)(b * NCHUNK + j)) * H_ + 2 * tid];
    float h0 = hs.x, h1 = hs.y;
    const unsigned short* base = cd + (size_t)(b * T_ + j * CHUNK) * (H_ * 2) + 4 * tid;
    float* ob = out + (size_t)(b * T_ + j * CHUNK) * H_ + 2 * tid;
    #pragma unroll 8
    for (int t = 0; t < CHUNK; ++t) {
        uint2 v = *(const uint2*)(base + (size_t)t * (H_ * 2));
        h0 = fmaf(bf_lo(v.x), h0, bf_hi(v.x));
        h1 = fmaf(bf_lo(v.y), h1, bf_hi(v.y));
        *(float2*)(ob + (size_t)t * H_) = make_float2(h0, h1);
    }
}

// ---------------------------------------------------------------------------
extern "C" void kernel_launch(void* const* d_in, const int* in_sizes, int n_in,
                              void* d_out, int out_size, void* d_ws, size_t ws_size,
                              hipStream_t stream)
{
    const float* x      = (const float*)d_in[0];
    const float* h_prev = (const float*)d_in[1];
    const float* W_h    = (const float*)d_in[2];
    const float* b_h    = (const float*)d_in[3];
    const float* W_z    = (const float*)d_in[4];
    const float* b_z    = (const float*)d_in[5];
    float* out = (float*)d_out;

    // xbf lives in d_out (dead until apply_scan overwrites all of it)
    unsigned short* xbf = (unsigned short*)d_out;               // 33.5 MB < 67 MB out

    char* ws = (char*)d_ws;
    unsigned short* cd = (unsigned short*)ws;                   // M*H*(c,d) bf16 = 67.1 MB
    size_t cd_bytes = (size_t)M_ * H_ * 2 * sizeof(unsigned short);
    unsigned short* Wf = (unsigned short*)(ws + cd_bytes);      // 1024*512 bf16 = 1 MB
    size_t wf_bytes = (size_t)2 * H_ * D_ * sizeof(unsigned short);
    float* Cagg   = (float*)(ws + cd_bytes + wf_bytes);         // 1 MB each
    float* Dagg   = Cagg + (size_t)B_ * NCHUNK * H_;
    float* Hstart = Dagg + (size_t)B_ * NCHUNK * H_;

    // 0) convert inputs to bf16 (single launch)
    {
        int total = M_ * D_ / 4 + 2 * (H_ * D_ / 4);
        conv_all<<<dim3((total + 255) / 256), dim3(256), 0, stream>>>(x, W_z, W_h, xbf, Wf);
    }
    // 1) dual GEMM + activation -> (c,d) bf16 pairs
    gemm_cd<<<dim3((M_ / 128) * (H_ / 128)), dim3(256), 0, stream>>>(
        xbf, Wf, b_z, b_h, cd);
    // 2) chunk-local aggregates
    chunk_scan<<<dim3(B_ * NCHUNK), dim3(256), 0, stream>>>(cd, Cagg, Dagg);
    // 3) inter-chunk sequential scan
    interchunk<<<dim3(32), dim3(64), 0, stream>>>(h_prev, Cagg, Dagg, Hstart);
    // 4) final apply -> d_out (overwrites xbf scratch)
    apply_scan<<<dim3(B_ * NCHUNK), dim3(256), 0, stream>>>(cd, Hstart, out);
}